// Round 1
// baseline (38.907 us; speedup 1.0000x reference)
//
#include <hip/hip_runtime.h>
#include <math.h>

#define NCOL 8192
#define BT 256

static __device__ __forceinline__ int swz(int i) {
    // dword-granular XOR swizzle: row=i>>5, col=i&31, phys=(row<<5)|(col^row&31)
    return (i & ~31) | ((i & 31) ^ ((i >> 5) & 31));
}

// exact double constants
#define MZM_LOSS_D 0.8912509381337456   // 10^-0.05
#define YB_LOSS_D  0.9332543007969910   // 10^-0.03
#define MRR_LOSS_D 0.8912509381337456   // 10^-0.05

__global__ __launch_bounds__(BT)
void odp_main(const float* __restrict__ x, const float* __restrict__ w,
              const float* __restrict__ ntp, const float* __restrict__ nsp,
              const float* __restrict__ ntn, const float* __restrict__ nsn,
              float* __restrict__ out)
{
    __shared__ float  xs[NCOL];     // swizzled row of x
    __shared__ float  redf[8];      // [0..3] row-max |x| per wave, [4..7] max |w|
    __shared__ double redd[8];      // pos/neg partial sums per wave

    const int t = threadIdx.x;
    const int b = blockIdx.x;
    const float4* __restrict__ xrow4 = (const float4*)(x + (size_t)b * NCOL);
    const float4* __restrict__ w4    = (const float4*)w;

    // ---------------- pass A: stage row into LDS (swizzled) + maxes ----------
    float mx = 0.0f, mw = 0.0f;
#pragma unroll
    for (int k = 0; k < 8; ++k) {
        const int idx = t + BT * k;          // float4 index, lane-consecutive
        const float4 xv = xrow4[idx];
        const float4 wv = w4[idx];
        mx = fmaxf(mx, fmaxf(fmaxf(fabsf(xv.x), fabsf(xv.y)),
                             fmaxf(fabsf(xv.z), fabsf(xv.w))));
        mw = fmaxf(mw, fmaxf(fmaxf(fabsf(wv.x), fabsf(wv.y)),
                             fmaxf(fabsf(wv.z), fabsf(wv.w))));
        const int i0   = idx * 4;
        const int rb   = i0 & ~31;
        const int rowx = (i0 >> 5) & 31;
        xs[rb + (((i0 + 0) & 31) ^ rowx)] = xv.x;
        xs[rb + (((i0 + 1) & 31) ^ rowx)] = xv.y;
        xs[rb + (((i0 + 2) & 31) ^ rowx)] = xv.z;
        xs[rb + (((i0 + 3) & 31) ^ rowx)] = xv.w;
    }
#pragma unroll
    for (int off = 32; off; off >>= 1) {
        mx = fmaxf(mx, __shfl_down(mx, off));
        mw = fmaxf(mw, __shfl_down(mw, off));
    }
    const int wid = t >> 6;
    if ((t & 63) == 0) { redf[wid] = mx; redf[4 + wid] = mw; }
    __syncthreads();

    float inorm = fmaxf(fmaxf(redf[0], redf[1]), fmaxf(redf[2], redf[3]));
    float wnorm = fmaxf(fmaxf(redf[4], redf[5]), fmaxf(redf[6], redf[7]));
    inorm = (inorm <= 1e-9f) ? 1.0f : inorm;
    wnorm = (wnorm <= 1e-9f) ? 1.0f : wnorm;
    const double inv_d = 1.0 / (double)inorm;   // emulates correctly-rounded f32 div
    const float  iwn   = 1.0f / wnorm;
    const float  CYM   = (float)(YB_LOSS_D * MZM_LOSS_D);

    // ---------------- pass C: per-thread contiguous 32 elems + halo ----------
    const int base = t << 5;        // logical & phys row base (row == t)
    const int xrt  = t & 31;
    float q[36];                    // q[c+2] <-> element base+c ; halo at 0,1,34,35
    unsigned pmask = 0;             // t_pos bits

#pragma unroll
    for (int c = 0; c < 32; ++c) {
        const float xr = xs[base + (c ^ xrt)];
        pmask |= (xr > 0.0f) ? (1u << c) : 0u;
        const float ax = fabsf(xr);
        const float t1 = (float)((double)ax * inv_d);  // == f32(ax/inorm)
        q[c + 2] = rintf(t1 * 255.0f);
    }
    q[0] = 0.0f; q[1] = 0.0f; q[34] = 0.0f; q[35] = 0.0f;
    if (t > 0) {
        const int r = t - 1, rb2 = r << 5, rx = r & 31;
        const float a0 = fabsf(xs[rb2 + (30 ^ rx)]);
        const float a1 = fabsf(xs[rb2 + (31 ^ rx)]);
        q[0] = rintf((float)((double)a0 * inv_d) * 255.0f);
        q[1] = rintf((float)((double)a1 * inv_d) * 255.0f);
    }
    if (t < BT - 1) {
        const int r = t + 1, rb2 = r << 5, rx = r & 31;
        const float a0 = fabsf(xs[rb2 + (0 ^ rx)]);
        const float a1 = fabsf(xs[rb2 + (1 ^ rx)]);
        q[34] = rintf((float)((double)a0 * inv_d) * 255.0f);
        q[35] = rintf((float)((double)a1 * inv_d) * 255.0f);
    }

    double accp = 0.0, accn = 0.0;
    const float4* __restrict__ wrow4 = (const float4*)(w + base);
#pragma unroll
    for (int g = 0; g < 8; ++g) {
        const float4 wv4 = wrow4[g];
        const float wc[4] = { wv4.x, wv4.y, wv4.z, wv4.w };
#pragma unroll
        for (int j = 0; j < 4; ++j) {
            const int c = g * 4 + j;
            const float conv = q[c + 2] + 0.01f   * (q[c + 1] + q[c + 3])
                                        + 0.0025f * (q[c]     + q[c + 4]);
            const float l  = conv * (10.0f / 255.0f);
            const float wv = wc[j];
            const float m  = l * (fabsf(wv) * iwn) * CYM;
            const bool  wpos = (wv >= 0.0f);
            const bool  tpos = ((pmask >> c) & 1u) != 0u;
            const double md = (double)m;
            if (wpos == tpos) accp += md; else accn += md;
        }
    }

    // fold interior conv-sum weight, then edge corrections (4 elements / row)
    const double E_MID = 1.0 + 2.0 * (double)0.01f + 2.0 * (double)0.0025f;
    const double DE0   = -((double)0.01f + (double)0.0025f);  // i=0, N-1
    const double DE1   = -((double)0.0025f);                  // i=1, N-2
    accp *= E_MID; accn *= E_MID;

    if (t == 0) {
#pragma unroll
        for (int c = 0; c < 2; ++c) {
            const float conv = q[c + 2] + 0.01f   * (q[c + 1] + q[c + 3])
                                        + 0.0025f * (q[c]     + q[c + 4]);
            const float l  = conv * (10.0f / 255.0f);
            const float wv = w[base + c];
            const float m  = l * (fabsf(wv) * iwn) * CYM;
            const double de = (c == 0) ? DE0 : DE1;
            const bool match = ((wv >= 0.0f) == (((pmask >> c) & 1u) != 0u));
            if (match) accp += de * (double)m; else accn += de * (double)m;
        }
    }
    if (t == BT - 1) {
#pragma unroll
        for (int c = 30; c < 32; ++c) {
            const float conv = q[c + 2] + 0.01f   * (q[c + 1] + q[c + 3])
                                        + 0.0025f * (q[c]     + q[c + 4]);
            const float l  = conv * (10.0f / 255.0f);
            const float wv = w[base + c];
            const float m  = l * (fabsf(wv) * iwn) * CYM;
            const double de = (c == 31) ? DE0 : DE1;   // i=N-1 gets DE0, i=N-2 DE1
            const bool match = ((wv >= 0.0f) == (((pmask >> c) & 1u) != 0u));
            if (match) accp += de * (double)m; else accn += de * (double)m;
        }
    }

    // ---------------- block reduce (double) + scalar tail ---------------------
#pragma unroll
    for (int off = 32; off; off >>= 1) {
        accp += __shfl_down(accp, off);
        accn += __shfl_down(accn, off);
    }
    if ((t & 63) == 0) { redd[wid] = accp; redd[4 + wid] = accn; }
    __syncthreads();

    if (t == 0) {
        const double ps = ((redd[0] + redd[1]) + (redd[2] + redd[3])) * MRR_LOSS_D;
        const double ns = ((redd[4] + redd[5]) + (redd[6] + redd[7])) * MRR_LOSS_D;

        const float thermal_f = 3.3135576e-12f;   // f32(4*kB*T*Hz/R)
        const float shot_f    = 3.204353268e-9f;  // f32(2*qE*Hz)

        double tp_ = ps + 1e-12 + (double)(ntp[b] * thermal_f);
        tp_ *= (double)(1.0f + nsp[b] * shot_f);   // == *1.0 in f32, faithful
        double tn_ = ns + 1e-12 + (double)(ntn[b] * thermal_f);
        tn_ *= (double)(1.0f + nsn[b] * shot_f);

        const double cur = tp_ - tn_;
        double v = fabs(cur * 100.0);
        v = fmin(v, 1.0);
        const double va  = rint(v * 255.0) * (1.0 / 255.0);
        const double sgn = (cur >= 0.0) ? 1.0 : -1.0;
        const double scale = (double)wnorm /
            (10.0 * 100.0 * MRR_LOSS_D * YB_LOSS_D * MZM_LOSS_D);
        out[b] = (float)(va * sgn * scale * (double)inorm);
    }
}

extern "C" void kernel_launch(void* const* d_in, const int* in_sizes, int n_in,
                              void* d_out, int out_size, void* d_ws, size_t ws_size,
                              hipStream_t stream) {
    const float* x   = (const float*)d_in[0];
    const float* w   = (const float*)d_in[1];
    const float* ntp = (const float*)d_in[2];
    const float* nsp = (const float*)d_in[3];
    const float* ntn = (const float*)d_in[4];
    const float* nsn = (const float*)d_in[5];
    float* out = (float*)d_out;
    odp_main<<<dim3(out_size), dim3(BT), 0, stream>>>(x, w, ntp, nsp, ntn, nsn, out);
}